// Round 19
// baseline (1943.629 us; speedup 1.0000x reference)
//
#include <hip/hip_runtime.h>
#include <cstdint>
#include <cstddef>

#define D_MODEL 512
#define NHEAD   8
#define DH      64
#define B_SZ    4
#define L_SEQ   2048
#define U_TOP   38          // int(5*ln(2048)) = 38
#define QPB     8           // queries per block (selection: 1 per wave)

// monotone float<->uint mapping (order-preserving, exact)
__device__ __forceinline__ unsigned mapmono(float f) {
    unsigned u = __float_as_uint(f);
    return (u & 0x80000000u) ? ~u : (u | 0x80000000u);
}

// ---------------- fp32 GEMM: C(8192x512) = A @ W + b ----------------
// Accurate tiled version for V and the output projection (order-insensitive).
// MODE 0: C row-major (b,l,dm)   MODE 1: scatter to (b,h,l,d)
template<int MODE>
__global__ __launch_bounds__(256)
void gemm512(const float* __restrict__ A, const float* __restrict__ W,
             const float* __restrict__ bias, float* __restrict__ C)
{
    __shared__ float As[16][68];
    __shared__ float Bs[16][68];
    const int tid  = threadIdx.x;
    const int row0 = blockIdx.x * 64;
    const int col0 = blockIdx.y * 64;
    const int ty = tid >> 4, tx = tid & 15;
    float acc[4][4] = {};

    for (int kt = 0; kt < D_MODEL; kt += 16) {
        {
            const int m = tid >> 2, k = (tid & 3) << 2;
            const float4 a = *reinterpret_cast<const float4*>(
                &A[(size_t)(row0 + m) * D_MODEL + kt + k]);
            As[k + 0][m] = a.x; As[k + 1][m] = a.y;
            As[k + 2][m] = a.z; As[k + 3][m] = a.w;
        }
        {
            const int k = tid >> 4, n = (tid & 15) << 2;
            *reinterpret_cast<float4*>(&Bs[k][n]) =
                *reinterpret_cast<const float4*>(
                    &W[(size_t)(kt + k) * D_MODEL + col0 + n]);
        }
        __syncthreads();
        #pragma unroll
        for (int kk = 0; kk < 16; ++kk) {
            const float4 a4 = *reinterpret_cast<const float4*>(&As[kk][ty << 2]);
            const float4 b4 = *reinterpret_cast<const float4*>(&Bs[kk][tx << 2]);
            const float av[4] = {a4.x, a4.y, a4.z, a4.w};
            const float bv[4] = {b4.x, b4.y, b4.z, b4.w};
            #pragma unroll
            for (int i = 0; i < 4; ++i)
                #pragma unroll
                for (int j = 0; j < 4; ++j)
                    acc[i][j] += av[i] * bv[j];
        }
        __syncthreads();
    }

    #pragma unroll
    for (int i = 0; i < 4; ++i) {
        const int r = row0 + (ty << 2) + i;
        const int cb = col0 + (tx << 2);
        float4 v;
        v.x = acc[i][0] + bias[cb + 0];
        v.y = acc[i][1] + bias[cb + 1];
        v.z = acc[i][2] + bias[cb + 2];
        v.w = acc[i][3] + bias[cb + 3];
        if (MODE == 0) {
            *reinterpret_cast<float4*>(&C[(size_t)r * D_MODEL + cb]) = v;
        } else {
            const int b = r >> 11, l = r & (L_SEQ - 1);
            const int h = cb >> 6, d = cb & 63;
            *reinterpret_cast<float4*>(
                &C[(size_t)((b * NHEAD + h) * L_SEQ + l) * DH + d]) = v;
        }
    }
}

// ----- np-replica GEMM for Q,K: SINGLE K-panel sequential FMA chain -----
// (LOCKED arithmetic — passed round 9. Per C element: ONE fp32 accumulator,
// FMA over k=0..511 ascending, then one fp32 bias add.)
__global__ __launch_bounds__(256)
void chain_gemm_qk(const float* __restrict__ x, const float* __restrict__ W,
                   const float* __restrict__ bias, float* __restrict__ Out)
{
    const int tid  = threadIdx.x;
    const int col  = blockIdx.y * 256 + tid;        // 0..511
    const int row0 = blockIdx.x * 16;               // 16 rows per block

    float acc[16];
    #pragma unroll
    for (int r = 0; r < 16; ++r) acc[r] = 0.f;

    for (int k = 0; k < D_MODEL; k += 4) {          // one panel: k = 0..511
        const float w0 = W[(size_t)(k + 0) * D_MODEL + col];
        const float w1 = W[(size_t)(k + 1) * D_MODEL + col];
        const float w2 = W[(size_t)(k + 2) * D_MODEL + col];
        const float w3 = W[(size_t)(k + 3) * D_MODEL + col];
        #pragma unroll
        for (int r = 0; r < 16; ++r) {
            const float4 xv = *reinterpret_cast<const float4*>(
                &x[(size_t)(row0 + r) * D_MODEL + k]);
            acc[r] = __fmaf_rn(xv.x, w0, acc[r]);
            acc[r] = __fmaf_rn(xv.y, w1, acc[r]);
            acc[r] = __fmaf_rn(xv.z, w2, acc[r]);
            acc[r] = __fmaf_rn(xv.w, w3, acc[r]);
        }
    }

    const float bc = bias[col];
    const int h = col >> 6, d = col & 63;
    #pragma unroll
    for (int r = 0; r < 16; ++r) {
        const int row = row0 + r;
        const int b = row >> 11, l = row & (L_SEQ - 1);
        Out[((size_t)((b * NHEAD + h) * L_SEQ + l)) * DH + d] =
            __fadd_rn(acc[r], bc);
    }
}

// ---- attention: BLAS-chain scores (LOCKED bits) -> exact fp32 top-38 ----
// r19 restructure (arithmetic bit-identical; selection verbatim r14):
//  * NO K LDS tile. Wave w computes ALL 8 queries over ITS 256-key slice
//    (4 keys/lane, acc[8][4]): each global K b128 feeds 32 FMA4s (8x the
//    amortization of r14, whose 512 ds_read_b128/query = ~655us/CU port
//    floor was the measured bottleneck).
//  * K read straight from global: per dc, 4 lane-strided b128; the 64B
//    line per (lane,slot) is reused across 4 consecutive dc -> ~4KB live
//    per wave, 32KB/CU = L1-resident. Q via wave-uniform LDS b128.
//  * mapped scores -> 64KB LDS slab[q][k] (b32 conflict-free), 1 barrier,
//    wave q reads its query back (32/lane) and runs r14's selection
//    verbatim (key = j*64+lane, ascending preserved).
__global__ __launch_bounds__(512, 2)
void attn_kernel(const float* __restrict__ Q, const float* __restrict__ K,
                 const float* __restrict__ V, float* __restrict__ ctx)
{
    __shared__ float Qs[QPB][DH];          // 2 KB
    __shared__ float slab[QPB * L_SEQ];    // 64 KB mapped scores [q][k]
    __shared__ int   kidx[QPB][64];        // 2 KB  kept keys (ascending)
    __shared__ float kwgt[QPB][64];        // 2 KB  kept exp-weights

    // XCD swizzle: all 256 q-tiles of a (b,h) on one XCD (K/V L2-resident)
    const int bid = blockIdx.x;            // 0..8191
    const int xcd = bid & 7, jrem = bid >> 3;
    const int bh  = xcd * 4 + (jrem >> 8); // 0..31
    const int qt  = jrem & 255;            // 0..255
    const int b   = bh >> 3, h = bh & 7;

    const float* __restrict__ Qbh = Q + (size_t)bh * L_SEQ * DH;
    const float* __restrict__ Kbh = K + (size_t)bh * L_SEQ * DH;
    const float* __restrict__ Vbh = V + (size_t)bh * L_SEQ * DH;

    const int tid = threadIdx.x;
    const int wave = tid >> 6, lane = tid & 63;

    // stage Q tile (8x64): one float per thread, coalesced
    Qs[tid >> 6][tid & 63] =
        Qbh[(size_t)(qt * QPB + (tid >> 6)) * DH + (tid & 63)];
    __syncthreads();

    // ---- score phase: wave w covers keys [256w, 256w+256), all 8 q ----
    float acc[8][4];
    #pragma unroll
    for (int q = 0; q < 8; ++q)
        #pragma unroll
        for (int j = 0; j < 4; ++j) acc[q][j] = 0.f;

    const int k0 = wave * 256 + lane;      // slot j adds j*64

    #pragma unroll
    for (int dc = 0; dc < 16; ++dc) {
        float4 kv[4];
        #pragma unroll
        for (int j = 0; j < 4; ++j)
            kv[j] = *reinterpret_cast<const float4*>(
                &Kbh[(size_t)(k0 + j * 64) * DH + (dc << 2)]);
        #pragma unroll
        for (int q = 0; q < 8; ++q) {
            const float4 p = *reinterpret_cast<const float4*>(&Qs[q][dc << 2]);
            #pragma unroll
            for (int j = 0; j < 4; ++j) {   // LOCKED chain: dc asc, x,y,z,w
                acc[q][j] = __fmaf_rn(p.x, kv[j].x, acc[q][j]);
                acc[q][j] = __fmaf_rn(p.y, kv[j].y, acc[q][j]);
                acc[q][j] = __fmaf_rn(p.z, kv[j].z, acc[q][j]);
                acc[q][j] = __fmaf_rn(p.w, kv[j].w, acc[q][j]);
            }
        }
    }

    // scale (/8 exact) + map + write slab (b32, lane-consecutive)
    #pragma unroll
    for (int q = 0; q < 8; ++q)
        #pragma unroll
        for (int j = 0; j < 4; ++j)
            slab[q * L_SEQ + wave * 256 + j * 64 + lane] =
                __uint_as_float(mapmono(__fmul_rn(acc[q][j], 0.125f)));
    __syncthreads();

    // ---- selection phase: wave q owns query q (verbatim r14 logic) ----
    const int qg = wave;
    float s[32];                            // already-mapped scores
    #pragma unroll
    for (int j = 0; j < 32; ++j)
        s[j] = slab[qg * L_SEQ + j * 64 + lane];

    // exact fp32 38th-largest: binary search in mapped-uint space.
    // count = sum_j popcount(ballot(u_j >= mid)) -> v_cmp + s_bcnt1 (SALU)
    unsigned long long lo = 0ull, hi = 0x100000000ull;
    while (hi - lo > 1ull) {
        const unsigned mid = (unsigned)((lo + hi) >> 1);
        int cnt = 0;
        #pragma unroll
        for (int j = 0; j < 32; ++j)
            cnt += (int)__popcll(__ballot(__float_as_uint(s[j]) >= mid));
        if (cnt >= U_TOP) lo = mid; else hi = mid;
    }
    const unsigned thrU = (unsigned)lo;     // mapped bits of the 38th value

    // row max in mapped space (top-1 always kept)
    unsigned um = 0u;
    #pragma unroll
    for (int j = 0; j < 32; ++j) {
        const unsigned ub = __float_as_uint(s[j]);
        um = um > ub ? um : ub;
    }
    #pragma unroll
    for (int off = 32; off; off >>= 1) {
        const unsigned o = (unsigned)__shfl_xor((int)um, off);
        um = um > o ? um : o;
    }
    const float mrow = __uint_as_float((um & 0x80000000u) ? (um & 0x7FFFFFFFu) : ~um);

    // compact kept keys (ascending key order: j asc, lane asc) via ballot
    int base = 0; float lsum = 0.f;
    #pragma unroll
    for (int j = 0; j < 32; ++j) {
        const unsigned ub = __float_as_uint(s[j]);
        const bool keep = (ub >= thrU);     // == !(score < thr), np semantics
        const unsigned long long mk = __ballot(keep);
        if (keep) {
            const float sc = __uint_as_float((ub & 0x80000000u) ? (ub & 0x7FFFFFFFu) : ~ub);
            const float w = __expf(sc - mrow);
            const int pos = base + (int)__popcll(mk & ((1ull << lane) - 1ull));
            if (pos < 64) {
                kidx[qg][pos] = (j << 6) + lane;
                kwgt[qg][pos] = w;
            }
            lsum += w;
        }
        base += (int)__popcll(mk);
    }
    #pragma unroll
    for (int off = 32; off; off >>= 1) lsum += __shfl_xor(lsum, off);
    const int nk = base < 64 ? base : 64;

    // ctx[d] = (sum over kept, ascending key order) w * V[k][d] / Z
    // 8-deep load pipeline; FMA chain order preserved (ascending i)
    float acc2 = 0.f;
    int i = 0;
    for (; i + 8 <= nk; i += 8) {
        float wv[8], vv[8];
        #pragma unroll
        for (int u = 0; u < 8; ++u) {
            wv[u] = kwgt[qg][i + u];
            vv[u] = Vbh[(size_t)kidx[qg][i + u] * DH + lane];
        }
        #pragma unroll
        for (int u = 0; u < 8; ++u)
            acc2 = __fmaf_rn(wv[u], vv[u], acc2);
    }
    for (; i < nk; ++i)
        acc2 = __fmaf_rn(kwgt[qg][i], Vbh[(size_t)kidx[qg][i] * DH + lane], acc2);
    acc2 /= lsum;

    const int l = qt * QPB + qg;
    ctx[((size_t)(b * L_SEQ + l)) * D_MODEL + h * DH + lane] = acc2;
}

extern "C" void kernel_launch(void* const* d_in, const int* in_sizes, int n_in,
                              void* d_out, int out_size, void* d_ws, size_t ws_size,
                              hipStream_t stream) {
    (void)in_sizes; (void)n_in; (void)out_size; (void)ws_size;
    const float* x  = (const float*)d_in[0];
    const float* Wq = (const float*)d_in[1];
    const float* bq = (const float*)d_in[2];
    const float* Wk = (const float*)d_in[3];
    const float* bk = (const float*)d_in[4];
    const float* Wv = (const float*)d_in[5];
    const float* bv = (const float*)d_in[6];
    const float* Wo = (const float*)d_in[7];
    const float* bo = (const float*)d_in[8];
    float* out = (float*)d_out;

    // ws: Qf | Kf | V | ctx = 4 x 16.78 MB = 67.1 MB
    const size_t NE = (size_t)B_SZ * NHEAD * L_SEQ * DH;   // 4.19e6
    float* Qf = (float*)d_ws;
    float* Kf = Qf + NE;
    float* Vw = Kf + NE;
    float* Cw = Vw + NE;

    const dim3 gq(512, 2), g(128, 8), blk(256);
    chain_gemm_qk<<<gq, blk, 0, stream>>>(x, Wq, bq, Qf);
    chain_gemm_qk<<<gq, blk, 0, stream>>>(x, Wk, bk, Kf);
    gemm512<1>   <<<g,  blk, 0, stream>>>(x, Wv, bv, Vw);
    attn_kernel  <<<dim3(8192), dim3(512), 0, stream>>>(Qf, Kf, Vw, Cw);
    gemm512<0>   <<<g,  blk, 0, stream>>>(Cw, Wo, bo, out);
}

// Round 20
// 1210.411 us; speedup vs baseline: 1.6058x; 1.6058x over previous
//
#include <hip/hip_runtime.h>
#include <cstdint>
#include <cstddef>

#define D_MODEL 512
#define NHEAD   8
#define DH      64
#define B_SZ    4
#define L_SEQ   2048
#define U_TOP   38          // int(5*ln(2048)) = 38
#define QPB     8           // queries per block (1 per wave)
#define KT      128         // key tile staged in LDS

// monotone float<->uint mapping (order-preserving, exact)
__device__ __forceinline__ unsigned mapmono(float f) {
    unsigned u = __float_as_uint(f);
    return (u & 0x80000000u) ? ~u : (u | 0x80000000u);
}

// ---------------- fp32 GEMM: C(8192x512) = A @ W + b ----------------
// Accurate tiled version for V and the output projection (order-insensitive).
// MODE 0: C row-major (b,l,dm)   MODE 1: scatter to (b,h,l,d)
template<int MODE>
__global__ __launch_bounds__(256)
void gemm512(const float* __restrict__ A, const float* __restrict__ W,
             const float* __restrict__ bias, float* __restrict__ C)
{
    __shared__ float As[16][68];
    __shared__ float Bs[16][68];
    const int tid  = threadIdx.x;
    const int row0 = blockIdx.x * 64;
    const int col0 = blockIdx.y * 64;
    const int ty = tid >> 4, tx = tid & 15;
    float acc[4][4] = {};

    for (int kt = 0; kt < D_MODEL; kt += 16) {
        {
            const int m = tid >> 2, k = (tid & 3) << 2;
            const float4 a = *reinterpret_cast<const float4*>(
                &A[(size_t)(row0 + m) * D_MODEL + kt + k]);
            As[k + 0][m] = a.x; As[k + 1][m] = a.y;
            As[k + 2][m] = a.z; As[k + 3][m] = a.w;
        }
        {
            const int k = tid >> 4, n = (tid & 15) << 2;
            *reinterpret_cast<float4*>(&Bs[k][n]) =
                *reinterpret_cast<const float4*>(
                    &W[(size_t)(kt + k) * D_MODEL + col0 + n]);
        }
        __syncthreads();
        #pragma unroll
        for (int kk = 0; kk < 16; ++kk) {
            const float4 a4 = *reinterpret_cast<const float4*>(&As[kk][ty << 2]);
            const float4 b4 = *reinterpret_cast<const float4*>(&Bs[kk][tx << 2]);
            const float av[4] = {a4.x, a4.y, a4.z, a4.w};
            const float bv[4] = {b4.x, b4.y, b4.z, b4.w};
            #pragma unroll
            for (int i = 0; i < 4; ++i)
                #pragma unroll
                for (int j = 0; j < 4; ++j)
                    acc[i][j] += av[i] * bv[j];
        }
        __syncthreads();
    }

    #pragma unroll
    for (int i = 0; i < 4; ++i) {
        const int r = row0 + (ty << 2) + i;
        const int cb = col0 + (tx << 2);
        float4 v;
        v.x = acc[i][0] + bias[cb + 0];
        v.y = acc[i][1] + bias[cb + 1];
        v.z = acc[i][2] + bias[cb + 2];
        v.w = acc[i][3] + bias[cb + 3];
        if (MODE == 0) {
            *reinterpret_cast<float4*>(&C[(size_t)r * D_MODEL + cb]) = v;
        } else {
            const int b = r >> 11, l = r & (L_SEQ - 1);
            const int h = cb >> 6, d = cb & 63;
            *reinterpret_cast<float4*>(
                &C[(size_t)((b * NHEAD + h) * L_SEQ + l) * DH + d]) = v;
        }
    }
}

// ----- np-replica GEMM for Q,K: SINGLE K-panel sequential FMA chain -----
// (LOCKED arithmetic — passed round 9. Per C element: ONE fp32 accumulator,
// FMA over k=0..511 ascending, then one fp32 bias add.)
__global__ __launch_bounds__(256)
void chain_gemm_qk(const float* __restrict__ x, const float* __restrict__ W,
                   const float* __restrict__ bias, float* __restrict__ Out)
{
    const int tid  = threadIdx.x;
    const int col  = blockIdx.y * 256 + tid;        // 0..511
    const int row0 = blockIdx.x * 16;               // 16 rows per block

    float acc[16];
    #pragma unroll
    for (int r = 0; r < 16; ++r) acc[r] = 0.f;

    for (int k = 0; k < D_MODEL; k += 4) {          // one panel: k = 0..511
        const float w0 = W[(size_t)(k + 0) * D_MODEL + col];
        const float w1 = W[(size_t)(k + 1) * D_MODEL + col];
        const float w2 = W[(size_t)(k + 2) * D_MODEL + col];
        const float w3 = W[(size_t)(k + 3) * D_MODEL + col];
        #pragma unroll
        for (int r = 0; r < 16; ++r) {
            const float4 xv = *reinterpret_cast<const float4*>(
                &x[(size_t)(row0 + r) * D_MODEL + k]);
            acc[r] = __fmaf_rn(xv.x, w0, acc[r]);
            acc[r] = __fmaf_rn(xv.y, w1, acc[r]);
            acc[r] = __fmaf_rn(xv.z, w2, acc[r]);
            acc[r] = __fmaf_rn(xv.w, w3, acc[r]);
        }
    }

    const float bc = bias[col];
    const int h = col >> 6, d = col & 63;
    #pragma unroll
    for (int r = 0; r < 16; ++r) {
        const int row = row0 + r;
        const int b = row >> 11, l = row & (L_SEQ - 1);
        Out[((size_t)((b * NHEAD + h) * L_SEQ + l)) * DH + d] =
            __fadd_rn(acc[r], bc);
    }
}

// ---- attention: BLAS-chain scores (LOCKED bits) -> exact fp32 top-38 ----
// r20 = r14 verbatim (the empirical optimum of this structure family):
//  * 512 thr / 8 waves / 1 query per wave, s[32] -> VGPR 64, zero spill
//  * single-buffered 32KB swizzled K tile, 39KB LDS -> ~15 waves/CU
//  * selection: ballot+popc binary search (SALU count), ballot compaction,
//    8-deep pipelined V gather
// Explored and REJECTED by measurement: 2q/wave regs (r16: spill),
// 2q/wave LDS-spill (r17: 70KB->24% occ), dbuf+prefetch (r18: same),
// K-direct-from-global (r19: uncoalesced VMEM). LDS>64KB or VGPR>64
// each cost 150-700us on this kernel.
__global__ __launch_bounds__(512, 4)
void attn_kernel(const float* __restrict__ Q, const float* __restrict__ K,
                 const float* __restrict__ V, float* __restrict__ ctx)
{
    __shared__ float Qs[QPB][DH];          // 2 KB
    __shared__ float Ks[KT * DH];          // 32 KB, elem = r*64 + (col ^ ((r&7)<<2))
    __shared__ int   kidx[QPB][64];        // 2 KB  kept keys (ascending)
    __shared__ float kwgt[QPB][64];        // 2 KB  kept exp-weights

    // XCD swizzle: all 256 q-tiles of a (b,h) on one XCD (K/V L2-resident)
    const int bid = blockIdx.x;
    const int xcd = bid & 7, jrem = bid >> 3;
    const int bh  = xcd * 4 + (jrem >> 8);   // 0..31
    const int qt  = jrem & 255;              // 0..255
    const int b   = bh >> 3, h = bh & 7;

    const float* __restrict__ Qbh = Q + (size_t)bh * L_SEQ * DH;
    const float* __restrict__ Kbh = K + (size_t)bh * L_SEQ * DH;
    const float* __restrict__ Vbh = V + (size_t)bh * L_SEQ * DH;

    const int tid = threadIdx.x;
    const int wave = tid >> 6, lane = tid & 63;
    const int qg = wave;                     // one query per wave

    {   // stage Q tile (8x64): one float per thread, coalesced
        const int q = tid >> 6, d = tid & 63;
        Qs[q][d] = Qbh[(size_t)(qt * QPB + q) * DH + d];
    }

    float s[32];

    #pragma unroll
    for (int t = 0; t < L_SEQ / KT; ++t) {        // 16 tiles, fully unrolled
        __syncthreads();
        #pragma unroll
        for (int c = 0; c < 4; ++c) {             // stage K tile, swizzled
            const int f = c * 2048 + tid * 4;
            const int r = f >> 6, col = f & 63;
            const int sidx = (r << 6) + (col ^ ((r & 7) << 2));
            *reinterpret_cast<float4*>(&Ks[sidx]) =
                *reinterpret_cast<const float4*>(&Kbh[(size_t)t * (KT * DH) + f]);
        }
        __syncthreads();

        // single FMA chain over d ascending per key — LOCKED order
        float v0 = 0.f, v1 = 0.f;
        #pragma unroll
        for (int dc = 0; dc < 16; ++dc) {
            const int sw = (dc ^ (lane & 7)) << 2;   // logical cols 4dc..4dc+3
            const float4 k0 = *reinterpret_cast<const float4*>(
                &Ks[(lane << 6) + sw]);
            const float4 k1 = *reinterpret_cast<const float4*>(
                &Ks[((64 + lane) << 6) + sw]);
            const float4 p = *reinterpret_cast<const float4*>(&Qs[qg][dc << 2]);
            v0 = __fmaf_rn(p.x, k0.x, v0);
            v0 = __fmaf_rn(p.y, k0.y, v0);
            v0 = __fmaf_rn(p.z, k0.z, v0);
            v0 = __fmaf_rn(p.w, k0.w, v0);
            v1 = __fmaf_rn(p.x, k1.x, v1);
            v1 = __fmaf_rn(p.y, k1.y, v1);
            v1 = __fmaf_rn(p.z, k1.z, v1);
            v1 = __fmaf_rn(p.w, k1.w, v1);
        }
        // /sqrt(64) = *0.125, exact
        s[2*t]     = __fmul_rn(v0, 0.125f);
        s[2*t + 1] = __fmul_rn(v1, 0.125f);
    }

    // map scores to monotone uint space (in place)
    #pragma unroll
    for (int j = 0; j < 32; ++j)
        s[j] = __uint_as_float(mapmono(s[j]));

    // exact fp32 38th-largest: binary search in mapped-uint space.
    // count = sum_j popcount(ballot(u_j >= mid)) -> v_cmp + s_bcnt1 (SALU)
    unsigned long long lo = 0ull, hi = 0x100000000ull;
    while (hi - lo > 1ull) {
        const unsigned mid = (unsigned)((lo + hi) >> 1);
        int cnt = 0;
        #pragma unroll
        for (int j = 0; j < 32; ++j)
            cnt += (int)__popcll(__ballot(__float_as_uint(s[j]) >= mid));
        if (cnt >= U_TOP) lo = mid; else hi = mid;
    }
    const unsigned thrU = (unsigned)lo;     // mapped bits of the 38th value

    // row max in mapped space (top-1 always kept)
    unsigned um = 0u;
    #pragma unroll
    for (int j = 0; j < 32; ++j) {
        const unsigned ub = __float_as_uint(s[j]);
        um = um > ub ? um : ub;
    }
    #pragma unroll
    for (int off = 32; off; off >>= 1) {
        const unsigned o = (unsigned)__shfl_xor((int)um, off);
        um = um > o ? um : o;
    }
    const float mrow = __uint_as_float((um & 0x80000000u) ? (um & 0x7FFFFFFFu) : ~um);

    // compact kept keys (ascending key order) via ballot prefix-sum
    int base = 0; float lsum = 0.f;
    #pragma unroll
    for (int j = 0; j < 32; ++j) {
        const unsigned ub = __float_as_uint(s[j]);
        const bool keep = (ub >= thrU);     // == !(score < thr), np semantics
        const unsigned long long mk = __ballot(keep);
        if (keep) {
            const float sc = __uint_as_float((ub & 0x80000000u) ? (ub & 0x7FFFFFFFu) : ~ub);
            const float w = __expf(sc - mrow);
            const int pos = base + (int)__popcll(mk & ((1ull << lane) - 1ull));
            if (pos < 64) {
                kidx[qg][pos] = ((j >> 1) << 7) + ((j & 1) << 6) + lane;
                kwgt[qg][pos] = w;
            }
            lsum += w;
        }
        base += (int)__popcll(mk);
    }
    #pragma unroll
    for (int off = 32; off; off >>= 1) lsum += __shfl_xor(lsum, off);
    const int nk = base < 64 ? base : 64;

    // ctx[d] = (sum over kept, ascending key order) w * V[k][d] / Z
    // 8-deep load pipeline; FMA chain order preserved (ascending i)
    float acc = 0.f;
    int i = 0;
    for (; i + 8 <= nk; i += 8) {
        float wv[8], vv[8];
        #pragma unroll
        for (int u = 0; u < 8; ++u) {
            wv[u] = kwgt[qg][i + u];
            vv[u] = Vbh[(size_t)kidx[qg][i + u] * DH + lane];
        }
        #pragma unroll
        for (int u = 0; u < 8; ++u)
            acc = __fmaf_rn(wv[u], vv[u], acc);
    }
    for (; i < nk; ++i)
        acc = __fmaf_rn(kwgt[qg][i], Vbh[(size_t)kidx[qg][i] * DH + lane], acc);
    acc /= lsum;

    const int l = qt * QPB + qg;
    ctx[((size_t)(b * L_SEQ + l)) * D_MODEL + h * DH + lane] = acc;
}

extern "C" void kernel_launch(void* const* d_in, const int* in_sizes, int n_in,
                              void* d_out, int out_size, void* d_ws, size_t ws_size,
                              hipStream_t stream) {
    (void)in_sizes; (void)n_in; (void)out_size; (void)ws_size;
    const float* x  = (const float*)d_in[0];
    const float* Wq = (const float*)d_in[1];
    const float* bq = (const float*)d_in[2];
    const float* Wk = (const float*)d_in[3];
    const float* bk = (const float*)d_in[4];
    const float* Wv = (const float*)d_in[5];
    const float* bv = (const float*)d_in[6];
    const float* Wo = (const float*)d_in[7];
    const float* bo = (const float*)d_in[8];
    float* out = (float*)d_out;

    // ws: Qf | Kf | V | ctx = 4 x 16.78 MB = 67.1 MB
    const size_t NE = (size_t)B_SZ * NHEAD * L_SEQ * DH;   // 4.19e6
    float* Qf = (float*)d_ws;
    float* Kf = Qf + NE;
    float* Vw = Kf + NE;
    float* Cw = Vw + NE;

    const dim3 gq(512, 2), g(128, 8), blk(256);
    chain_gemm_qk<<<gq, blk, 0, stream>>>(x, Wq, bq, Qf);
    chain_gemm_qk<<<gq, blk, 0, stream>>>(x, Wk, bk, Kf);
    gemm512<1>   <<<g,  blk, 0, stream>>>(x, Wv, bv, Vw);
    attn_kernel  <<<dim3(8192), dim3(512), 0, stream>>>(Qf, Kf, Vw, Cw);
    gemm512<0>   <<<g,  blk, 0, stream>>>(Cw, Wo, bo, out);
}